// Round 17
// baseline (1151.766 us; speedup 1.0000x reference)
//
#include <hip/hip_runtime.h>

#define NPER 4096
#define MS   1024
#define CIN  64
#define LCAP 384

typedef float  f32x4 __attribute__((ext_vector_type(4)));
typedef short  s16x8 __attribute__((ext_vector_type(8)));

// Exact d2 matching the numpy/XLA reference: per-component sub, rounded square,
// left-assoc sum. _rn forbids fma contraction -> bit-exact ball/argmax picks.
__device__ __forceinline__ float d2_exact(float ax, float ay, float az,
                                          float bx, float by, float bz) {
  float dx = __fsub_rn(ax, bx);
  float dy = __fsub_rn(ay, by);
  float dz = __fsub_rn(az, bz);
  return __fadd_rn(__fadd_rn(__fmul_rn(dx, dx), __fmul_rn(dy, dy)), __fmul_rn(dz, dz));
}

// f32 -> bf16 (RNE) bit pattern
__device__ __forceinline__ unsigned short f2bf(float f) {
  unsigned b = __float_as_uint(f);
  return (unsigned short)((b + 0x7FFFu + ((b >> 16) & 1u)) >> 16);
}

template <int CTRL, int RMASK>
__device__ __forceinline__ unsigned long long dpp_max_step(unsigned long long k) {
  int hi = (int)(unsigned)(k >> 32);
  int lo = (int)(unsigned)(k & 0xFFFFFFFFull);
  int thi = __builtin_amdgcn_update_dpp(hi, hi, CTRL, RMASK, 0xF, false);
  int tlo = __builtin_amdgcn_update_dpp(lo, lo, CTRL, RMASK, 0xF, false);
  unsigned long long t =
      ((unsigned long long)(unsigned)thi << 32) | (unsigned)tlo;
  return t > k ? t : k;
}

__device__ __forceinline__ unsigned long long u64max(unsigned long long a,
                                                    unsigned long long b) {
  return a > b ? a : b;
}

__device__ __forceinline__ unsigned long long wave_max_key(unsigned long long k) {
  k = dpp_max_step<0x111, 0xF>(k);  // row_shr:1
  k = dpp_max_step<0x112, 0xF>(k);  // row_shr:2
  k = dpp_max_step<0x114, 0xF>(k);  // row_shr:4
  k = dpp_max_step<0x118, 0xF>(k);  // row_shr:8
  k = dpp_max_step<0x142, 0xA>(k);  // row_bcast15
  k = dpp_max_step<0x143, 0xC>(k);  // row_bcast31 -> lane63 = wave max
  return k;
}

// R2-proven per-chain scan+butterfly (strict >, ascending j: lowest idx on tie)
#define SCAN_BFLY(PX, PY, PZ, DD, LX, LY, LZ, KOUT)                         \
  {                                                                         \
    float bd_ = -1.0f;                                                      \
    int bi_ = 0;                                                            \
    _Pragma("unroll") for (int j = 0; j < 16; ++j) {                        \
      float d2_ = d2_exact(PX[j], PY[j], PZ[j], LX, LY, LZ);                \
      float nd_ = fminf(DD[j], d2_);                                        \
      DD[j] = nd_;                                                          \
      if (nd_ > bd_) { bd_ = nd_; bi_ = t + j * 256; }                      \
    }                                                                       \
    KOUT = ((unsigned long long)__float_as_uint(bd_) << 32) |               \
           (unsigned)(~bi_);                                                \
    KOUT = wave_max_key(KOUT);                                              \
  }

// -------- FPS x2, PHASE-SHIFTED pipeline: one block per graph pair ---------
// R14 lesson: wave issue adds serially; both scans before one barrier leaves
// the post-barrier merge->coord chain (~400cy) unfilled. Fix: half-iteration
// phase shift. Per iteration (2 samples, 2 barriers):
//   mergeA(m) || scanB(m)  -> bar -> mergeB(m) || scanA(m+1) -> bar
// Each chain's merge/coord dependent latency completes under the OTHER
// chain's scan issue. Per-chain code (scan, butterfly, merge, parity
// double-buffer) is byte-identical to R2/R12-proven; barriers are a superset
// sync, so exactness is inherited.
__global__ __launch_bounds__(256) void fps_pipe2(const float* __restrict__ pos,
                                                 int* __restrict__ idx_out) {
  const int b0 = blockIdx.x * 2;  // graphs b0, b0+1
  const int t = threadIdx.x;
  __shared__ float4 sA[NPER];                           // 64 KB
  __shared__ float4 sB[NPER];                           // 64 KB
  __shared__ __align__(16) unsigned long long s_redA[2][4];
  __shared__ __align__(16) unsigned long long s_redB[2][4];
  const float* pA = pos + (size_t)b0 * NPER * 3;
  const float* pB = pos + (size_t)(b0 + 1) * NPER * 3;
  for (int i = t; i < NPER; i += 256) {
    sA[i] = make_float4(pA[i * 3], pA[i * 3 + 1], pA[i * 3 + 2], 0.f);
    sB[i] = make_float4(pB[i * 3], pB[i * 3 + 1], pB[i * 3 + 2], 0.f);
  }
  if (t == 0) {
    idx_out[b0 * MS] = 0;
    idx_out[(b0 + 1) * MS] = 0;
  }
  __syncthreads();

  float pxA[16], pyA[16], pzA[16], dA[16];
  float pxB[16], pyB[16], pzB[16], dB[16];
#pragma unroll
  for (int j = 0; j < 16; ++j) {
    float4 a = sA[t + j * 256];
    pxA[j] = a.x; pyA[j] = a.y; pzA[j] = a.z;
    dA[j] = __builtin_inff();
    float4 c = sB[t + j * 256];
    pxB[j] = c.x; pyB[j] = c.y; pzB[j] = c.z;
    dB[j] = __builtin_inff();
  }
  const int w = t >> 6;
  const int lane = t & 63;

  float lxA = sA[0].x, lyA = sA[0].y, lzA = sA[0].z;
  float lxB = sB[0].x, lyB = sB[0].y, lzB = sB[0].z;

  // ---- prologue: scanA(1) published into slot 1 ---------------------------
  {
    unsigned long long kA;
    SCAN_BFLY(pxA, pyA, pzA, dA, lxA, lyA, lzA, kA);
    if (lane == 63) s_redA[1][w] = kA;
  }
  __syncthreads();

  for (int m = 1; m < MS; ++m) {
    const int p = m & 1;
    // ---- mergeA(m): reads s_redA[p]; latency hidden under scanB ----------
    ulonglong2 a0 = *reinterpret_cast<const ulonglong2*>(&s_redA[p][0]);
    ulonglong2 a1 = *reinterpret_cast<const ulonglong2*>(&s_redA[p][2]);
    unsigned long long kAm = u64max(u64max(a0.x, a0.y), u64max(a1.x, a1.y));
    const int nxA = (int)(~(unsigned)(kAm & 0xFFFFFFFFull));
    if (t == 0) idx_out[b0 * MS + m] = nxA;
    float4 wpA = sA[nxA];  // broadcast read; result needed only next half-iter
    // ---- scanB(m): uses coordB(m-1); fills mergeA's latency --------------
    {
      unsigned long long kB;
      SCAN_BFLY(pxB, pyB, pzB, dB, lxB, lyB, lzB, kB);
      if (lane == 63) s_redB[p][w] = kB;
    }
    __syncthreads();
    // ---- mergeB(m): reads s_redB[p]; latency hidden under scanA(m+1) -----
    ulonglong2 c0 = *reinterpret_cast<const ulonglong2*>(&s_redB[p][0]);
    ulonglong2 c1 = *reinterpret_cast<const ulonglong2*>(&s_redB[p][2]);
    unsigned long long kBm = u64max(u64max(c0.x, c0.y), u64max(c1.x, c1.y));
    const int nxB = (int)(~(unsigned)(kBm & 0xFFFFFFFFull));
    if (t == 0) idx_out[(b0 + 1) * MS + m] = nxB;
    float4 wpB = sB[nxB];  // result needed only next half-iter
    // ---- scanA(m+1): uses coordA(m) just merged; publishes slot p^1 ------
    lxA = wpA.x; lyA = wpA.y; lzA = wpA.z;
    if (m + 1 < MS) {
      unsigned long long kA2;
      SCAN_BFLY(pxA, pyA, pzA, dA, lxA, lyA, lzA, kA2);
      if (lane == 63) s_redA[p ^ 1][w] = kA2;
    }
    lxB = wpB.x; lyB = wpB.y; lzB = wpB.z;
    __syncthreads();
  }
}

// ---- radius(top-64) + MFMA-bf16 MLP + masked neighbor max (R3, proven) ----
__global__ __launch_bounds__(512, 4) void radconv_kernel(
    const float* __restrict__ x, const float* __restrict__ pos,
    const int* __restrict__ idx,
    const float* __restrict__ W1, const float* __restrict__ B1,
    const float* __restrict__ W2, const float* __restrict__ B2,
    const float* __restrict__ W3, const float* __restrict__ B3,
    float* __restrict__ out) {
  const int t = threadIdx.x;
  const int g = blockIdx.x >> 9;          // graph
  const int qpair = blockIdx.x & 511;     // 512 blocks/graph * 2 queries
  const float* pb = pos + (size_t)g * NPER * 3;
  const float* xb = x + (size_t)g * NPER * CIN;

  __shared__ int s_cnt[2];
  __shared__ float s_ctr[2][4];
  __shared__ __align__(16) unsigned long long s_list[2][LCAP];  // 6 KB
  __shared__ int s_nbr[2][64];
  __shared__ __align__(16) unsigned short sFeat[2][64 * 104];   // 26 KB (reused as red)
  __shared__ __align__(16) unsigned short sW1[64 * 104];        // 13 KB  [col][k<=96pad]
  __shared__ __align__(16) unsigned short sW2[64 * 72];         // 9 KB   [col][k=64+pad]
  __shared__ __align__(16) unsigned short sW3[128 * 72];        // 18 KB

  if (t < 2) s_cnt[t] = 0;
  const int q0 = g * MS + qpair * 2;
  const int qiA = idx[q0], qiB = idx[q0 + 1];
  const float cAx = pb[qiA * 3], cAy = pb[qiA * 3 + 1], cAz = pb[qiA * 3 + 2];
  const float cBx = pb[qiB * 3], cBy = pb[qiB * 3 + 1], cBz = pb[qiB * 3 + 2];
  if (t == 0) { s_ctr[0][0] = cAx; s_ctr[0][1] = cAy; s_ctr[0][2] = cAz; }
  if (t == 1) { s_ctr[1][0] = cBx; s_ctr[1][1] = cBy; s_ctr[1][2] = cBz; }
  __syncthreads();  // B1: s_cnt zeroed

  // ---- search: 8 pts/thread, both queries --------------------------------
  {
    float pp[24];
    const float4* pv = (const float4*)(pb + (size_t)t * 24);
#pragma unroll
    for (int r = 0; r < 6; ++r) {
      float4 v = pv[r];
      pp[r * 4 + 0] = v.x; pp[r * 4 + 1] = v.y;
      pp[r * 4 + 2] = v.z; pp[r * 4 + 3] = v.w;
    }
#pragma unroll
    for (int jj = 0; jj < 8; ++jj) {
      const int j = t * 8 + jj;
      const float X = pp[jj * 3], Y = pp[jj * 3 + 1], Z = pp[jj * 3 + 2];
      float dA = d2_exact(X, Y, Z, cAx, cAy, cAz);
      if (dA <= 0.04f) {  // f32(0.04) == JAX's R*R
        int p = atomicAdd(&s_cnt[0], 1);
        if (p < LCAP)
          s_list[0][p] = ((unsigned long long)__float_as_uint(dA) << 32) | (unsigned)j;
      }
      float dB = d2_exact(X, Y, Z, cBx, cBy, cBz);
      if (dB <= 0.04f) {
        int p = atomicAdd(&s_cnt[1], 1);
        if (p < LCAP)
          s_list[1][p] = ((unsigned long long)__float_as_uint(dB) << 32) | (unsigned)j;
      }
    }
  }
  // ---- stage weights (bf16, transposed) — independent of search ----------
  for (int ee = t; ee < 64 * 64; ee += 512) {           // zero W1 k-pad 67..103
    int c = ee >> 6, kk = 67 + (ee & 63);
    if (kk < 104) sW1[c * 104 + kk] = 0;
  }
  for (int e = t; e < 67 * 64; e += 512) {              // W1t[c][k] = W1[k][c]
    int k = e >> 6, c = e & 63;
    sW1[c * 104 + k] = f2bf(W1[e]);
  }
  for (int e = t; e < 64 * 64; e += 512) {
    int k = e >> 6, c = e & 63;
    sW2[c * 72 + k] = f2bf(W2[e]);
  }
  for (int e = t; e < 64 * 128; e += 512) {
    int k = e >> 7, c = e & 127;
    sW3[c * 72 + k] = f2bf(W3[e]);
  }
  __syncthreads();  // B2: lists + weights ready

  const int w = t >> 6, lane = t & 63;
  const int c0 = min(min(s_cnt[0], LCAP), 64);
  const int c1 = min(min(s_cnt[1], LCAP), 64);

  // ---- exact top-64 by (d2, idx) via rank; 4 waves per query -------------
  {
    const int rq = w >> 2;
    const int nsurv = min(s_cnt[rq], LCAP);
    for (int e = (w & 3) * 64 + lane; e < nsurv; e += 256) {
      unsigned long long mykey = s_list[rq][e];
      int rank = 0;
      int o = 0;
      for (; o + 8 <= nsurv; o += 8) {
        unsigned long long k0 = s_list[rq][o + 0], k1 = s_list[rq][o + 1];
        unsigned long long k2 = s_list[rq][o + 2], k3 = s_list[rq][o + 3];
        unsigned long long k4 = s_list[rq][o + 4], k5 = s_list[rq][o + 5];
        unsigned long long k6 = s_list[rq][o + 6], k7 = s_list[rq][o + 7];
        rank += (k0 < mykey) + (k1 < mykey) + (k2 < mykey) + (k3 < mykey) +
                (k4 < mykey) + (k5 < mykey) + (k6 < mykey) + (k7 < mykey);
      }
      for (; o < nsurv; ++o) rank += (s_list[rq][o] < mykey) ? 1 : 0;
      if (rank < 64) s_nbr[rq][rank] = (int)(mykey & 0xFFFFFFFFull);
    }
  }
  __syncthreads();  // B3: nbr lists ready

  // ---- gather feat rows: [x_j bf16 (64) | rel (3) | 0 pad ... 96) --------
  {
    const int slot = t >> 2, part = t & 3;   // 128 slots x 4 parts
    const int gq = slot >> 6, s = slot & 63;
    const int cq = gq ? c1 : c0;
    unsigned short* frow = &sFeat[gq][s * 104];
    uint4 z; z.x = z.y = z.z = z.w = 0u;
    if (s < cq) {
      const int j = s_nbr[gq][s];
      const float4* xr = (const float4*)(xb + (size_t)j * CIN + part * 16);
      float4 v0 = xr[0], v1 = xr[1], v2 = xr[2], v3 = xr[3];
      uint4 w0, w1;
      w0.x = f2bf(v0.x) | ((unsigned)f2bf(v0.y) << 16);
      w0.y = f2bf(v0.z) | ((unsigned)f2bf(v0.w) << 16);
      w0.z = f2bf(v1.x) | ((unsigned)f2bf(v1.y) << 16);
      w0.w = f2bf(v1.z) | ((unsigned)f2bf(v1.w) << 16);
      w1.x = f2bf(v2.x) | ((unsigned)f2bf(v2.y) << 16);
      w1.y = f2bf(v2.z) | ((unsigned)f2bf(v2.w) << 16);
      w1.z = f2bf(v3.x) | ((unsigned)f2bf(v3.y) << 16);
      w1.w = f2bf(v3.z) | ((unsigned)f2bf(v3.w) << 16);
      *(uint4*)(frow + part * 16) = w0;
      *(uint4*)(frow + part * 16 + 8) = w1;
      uint4 rz = z;
      if (part == 0) {
        const float cx = gq ? cBx : cAx, cy = gq ? cBy : cAy, cz = gq ? cBz : cAz;
        rz.x = f2bf(pb[j * 3] - cx) | ((unsigned)f2bf(pb[j * 3 + 1] - cy) << 16);
        rz.y = (unsigned)f2bf(pb[j * 3 + 2] - cz);
      }
      *(uint4*)(frow + 64 + part * 8) = rz;
    } else {
      *(uint4*)(frow + part * 16) = z;
      *(uint4*)(frow + part * 16 + 8) = z;
      *(uint4*)(frow + 64 + part * 8) = z;
    }
  }
  __syncthreads();  // B4: feat ready

  // ---- MFMA MLP: wave -> (query qq2, row tile mt) ------------------------
  const int qq2 = w >> 2;
  const int mt = w & 3;
  const int lo = lane & 15, hi = lane >> 4;
  unsigned short* F = &sFeat[qq2][0];
  const int arow = (16 * mt + lo) * 104;
  const int hrow = (16 * mt + hi * 4) * 104;

  {  // layer 1: K=96 (3 steps), N=64
    f32x4 acc[4];
#pragma unroll
    for (int n = 0; n < 4; ++n) {
      float bb = B1[n * 16 + lo];
      acc[n] = (f32x4){bb, bb, bb, bb};
    }
    s16x8 a0 = *(const s16x8*)(F + arow + 0 + hi * 8);
    s16x8 a1 = *(const s16x8*)(F + arow + 32 + hi * 8);
    s16x8 a2 = *(const s16x8*)(F + arow + 64 + hi * 8);
#pragma unroll
    for (int n = 0; n < 4; ++n) {
      const unsigned short* Bp = &sW1[(n * 16 + lo) * 104 + hi * 8];
      s16x8 b0 = *(const s16x8*)(Bp);
      s16x8 b1 = *(const s16x8*)(Bp + 32);
      s16x8 b2 = *(const s16x8*)(Bp + 64);
      acc[n] = __builtin_amdgcn_mfma_f32_16x16x32_bf16(a0, b0, acc[n], 0, 0, 0);
      acc[n] = __builtin_amdgcn_mfma_f32_16x16x32_bf16(a1, b1, acc[n], 0, 0, 0);
      acc[n] = __builtin_amdgcn_mfma_f32_16x16x32_bf16(a2, b2, acc[n], 0, 0, 0);
    }
#pragma unroll
    for (int n = 0; n < 4; ++n)
#pragma unroll
      for (int r = 0; r < 4; ++r)
        F[hrow + r * 104 + n * 16 + lo] = f2bf(fmaxf(acc[n][r], 0.f));
  }
  {  // layer 2: K=64 (2 steps), N=64
    f32x4 acc[4];
#pragma unroll
    for (int n = 0; n < 4; ++n) {
      float bb = B2[n * 16 + lo];
      acc[n] = (f32x4){bb, bb, bb, bb};
    }
    s16x8 a0 = *(const s16x8*)(F + arow + 0 + hi * 8);
    s16x8 a1 = *(const s16x8*)(F + arow + 32 + hi * 8);
#pragma unroll
    for (int n = 0; n < 4; ++n) {
      const unsigned short* Bp = &sW2[(n * 16 + lo) * 72 + hi * 8];
      s16x8 b0 = *(const s16x8*)(Bp);
      s16x8 b1 = *(const s16x8*)(Bp + 32);
      acc[n] = __builtin_amdgcn_mfma_f32_16x16x32_bf16(a0, b0, acc[n], 0, 0, 0);
      acc[n] = __builtin_amdgcn_mfma_f32_16x16x32_bf16(a1, b1, acc[n], 0, 0, 0);
    }
#pragma unroll
    for (int n = 0; n < 4; ++n)
#pragma unroll
      for (int r = 0; r < 4; ++r)
        F[hrow + r * 104 + n * 16 + lo] = f2bf(fmaxf(acc[n][r], 0.f));
  }
  float pm[8];
  {  // layer 3: K=64 (2 steps), N=128, fused masked row-max
    const int cq = qq2 ? c1 : c0;
    f32x4 acc[8];
#pragma unroll
    for (int n = 0; n < 8; ++n) {
      float bb = B3[n * 16 + lo];
      acc[n] = (f32x4){bb, bb, bb, bb};
    }
    s16x8 a0 = *(const s16x8*)(F + arow + 0 + hi * 8);
    s16x8 a1 = *(const s16x8*)(F + arow + 32 + hi * 8);
#pragma unroll
    for (int n = 0; n < 8; ++n) {
      const unsigned short* Bp = &sW3[(n * 16 + lo) * 72 + hi * 8];
      s16x8 b0 = *(const s16x8*)(Bp);
      s16x8 b1 = *(const s16x8*)(Bp + 32);
      acc[n] = __builtin_amdgcn_mfma_f32_16x16x32_bf16(a0, b0, acc[n], 0, 0, 0);
      acc[n] = __builtin_amdgcn_mfma_f32_16x16x32_bf16(a1, b1, acc[n], 0, 0, 0);
    }
#pragma unroll
    for (int n = 0; n < 8; ++n) {
      float v = -1e30f;
#pragma unroll
      for (int r = 0; r < 4; ++r) {
        int row = 16 * mt + hi * 4 + r;
        if (row < cq) v = fmaxf(v, fmaxf(acc[n][r], 0.f));
      }
      pm[n] = v;
    }
  }
  __syncthreads();  // B5: all sFeat reads done -> reuse as reduction buffer

  float* red = (float*)&sFeat[0][0];  // [2][128][17] floats
#pragma unroll
  for (int n = 0; n < 8; ++n)
    red[((qq2 * 128) + n * 16 + lo) * 17 + mt * 4 + hi] = pm[n];
  __syncthreads();  // B6

  if (t < 256) {
    const int gq = t >> 7, cc = t & 127;
    const float* rp = red + (gq * 128 + cc) * 17;
    float v = rp[0];
#pragma unroll
    for (int p = 1; p < 16; ++p) v = fmaxf(v, rp[p]);
    out[(size_t)(q0 + gq) * 128 + cc] = v;
  }
  if (t == 256 || t == 257) {
    const int gq = t - 256;
    const int qrow = q0 + gq;
    out[524288 + qrow * 3 + 0] = s_ctr[gq][0];
    out[524288 + qrow * 3 + 1] = s_ctr[gq][1];
    out[524288 + qrow * 3 + 2] = s_ctr[gq][2];
    out[536576 + qrow] = (float)g;
  }
}

extern "C" void kernel_launch(void* const* d_in, const int* in_sizes, int n_in,
                              void* d_out, int out_size, void* d_ws, size_t ws_size,
                              hipStream_t stream) {
  const float* x   = (const float*)d_in[0];
  const float* pos = (const float*)d_in[1];
  const float* W1  = (const float*)d_in[3];
  const float* B1  = (const float*)d_in[4];
  const float* W2  = (const float*)d_in[5];
  const float* B2  = (const float*)d_in[6];
  const float* W3  = (const float*)d_in[7];
  const float* B3  = (const float*)d_in[8];
  float* out = (float*)d_out;
  int* idx = (int*)d_ws;  // 4096 ints

  fps_pipe2<<<2, 256, 0, stream>>>(pos, idx);
  radconv_kernel<<<2048, 512, 0, stream>>>(x, pos, idx, W1, B1, W2, B2, W3, B3, out);
}

// Round 18
// 651.985 us; speedup vs baseline: 1.7666x; 1.7666x over previous
//
#include <hip/hip_runtime.h>

#define NPER 4096
#define MS   1024
#define CIN  64
#define LCAP 384

typedef float  f32x4 __attribute__((ext_vector_type(4)));
typedef short  s16x8 __attribute__((ext_vector_type(8)));

// Exact d2 matching the numpy/XLA reference: per-component sub, rounded square,
// left-assoc sum. _rn forbids fma contraction -> bit-exact ball/argmax picks.
__device__ __forceinline__ float d2_exact(float ax, float ay, float az,
                                          float bx, float by, float bz) {
  float dx = __fsub_rn(ax, bx);
  float dy = __fsub_rn(ay, by);
  float dz = __fsub_rn(az, bz);
  return __fadd_rn(__fadd_rn(__fmul_rn(dx, dx), __fmul_rn(dy, dy)), __fmul_rn(dz, dz));
}

// f32 -> bf16 (RNE) bit pattern
__device__ __forceinline__ unsigned short f2bf(float f) {
  unsigned b = __float_as_uint(f);
  return (unsigned short)((b + 0x7FFFu + ((b >> 16) & 1u)) >> 16);
}

template <int CTRL, int RMASK>
__device__ __forceinline__ unsigned long long dpp_max_step(unsigned long long k) {
  int hi = (int)(unsigned)(k >> 32);
  int lo = (int)(unsigned)(k & 0xFFFFFFFFull);
  int thi = __builtin_amdgcn_update_dpp(hi, hi, CTRL, RMASK, 0xF, false);
  int tlo = __builtin_amdgcn_update_dpp(lo, lo, CTRL, RMASK, 0xF, false);
  unsigned long long t =
      ((unsigned long long)(unsigned)thi << 32) | (unsigned)tlo;
  return t > k ? t : k;
}

__device__ __forceinline__ unsigned long long u64max(unsigned long long a,
                                                    unsigned long long b) {
  return a > b ? a : b;
}

// ---------------- FPS: one block per graph, 256 threads, 16 pts/thread ------
// R2-proven kernel, verbatim (measured 597-599 us across R2/R12). Per iter:
// register d2+min+best (linear strict-> chain) -> DPP butterfly (lane63 = wave
// max) -> lane63 writes key -> ONE barrier -> all threads redundantly reduce
// the 4 wave keys (broadcast b128 reads) -> winner coords via one b128 read.
// s_red is parity-double-buffered so no second barrier is needed.
// Issue-bound on its CU (~61% VALUBusy active-CU); 9 structural variants
// (wider, pk, tournament, prune, fused, top-2, 2x interleave, pipelined)
// all measured worse -> this is the empirical floor structure.
__global__ __launch_bounds__(256) void fps_kernel(const float* __restrict__ pos,
                                                  int* __restrict__ idx_out) {
  const int b = blockIdx.x;
  const int t = threadIdx.x;
  __shared__ float4 s_pos4[NPER];                       // 64 KB
  __shared__ __align__(16) unsigned long long s_red[2][4];
  const float* pb = pos + (size_t)b * NPER * 3;
  for (int i = t; i < NPER; i += 256)
    s_pos4[i] = make_float4(pb[i * 3], pb[i * 3 + 1], pb[i * 3 + 2], 0.f);
  if (t == 0) idx_out[b * MS] = 0;
  __syncthreads();

  float px[16], py[16], pz[16], dist[16];
#pragma unroll
  for (int j = 0; j < 16; ++j) {
    float4 p = s_pos4[t + j * 256];
    px[j] = p.x; py[j] = p.y; pz[j] = p.z;
    dist[j] = __builtin_inff();
  }
  const int w = t >> 6;
  const int lane = t & 63;

  float lx = s_pos4[0].x, ly = s_pos4[0].y, lz = s_pos4[0].z;

  for (int m = 1; m < MS; ++m) {
    float bd = -1.0f;
    int bi = 0;
#pragma unroll
    for (int j = 0; j < 16; ++j) {
      float d2 = d2_exact(px[j], py[j], pz[j], lx, ly, lz);
      float nd = fminf(dist[j], d2);
      dist[j] = nd;
      if (nd > bd) { bd = nd; bi = t + j * 256; }  // strict >: lowest idx on tie
    }
    // pack (dist_bits << 32) | ~idx : u64 max == max dist, tie -> min idx
    unsigned long long k =
        ((unsigned long long)__float_as_uint(bd) << 32) | (unsigned)(~bi);
    k = dpp_max_step<0x111, 0xF>(k);  // row_shr:1
    k = dpp_max_step<0x112, 0xF>(k);  // row_shr:2
    k = dpp_max_step<0x114, 0xF>(k);  // row_shr:4
    k = dpp_max_step<0x118, 0xF>(k);  // row_shr:8
    k = dpp_max_step<0x142, 0xA>(k);  // row_bcast15
    k = dpp_max_step<0x143, 0xC>(k);  // row_bcast31 -> lane63 = wave max
    const int par = m & 1;
    if (lane == 63) s_red[par][w] = k;
    __syncthreads();
    ulonglong2 ab = *reinterpret_cast<const ulonglong2*>(&s_red[par][0]);
    ulonglong2 cd = *reinterpret_cast<const ulonglong2*>(&s_red[par][2]);
    unsigned long long kb = u64max(u64max(ab.x, ab.y), u64max(cd.x, cd.y));
    const int nx = (int)(~(unsigned)(kb & 0xFFFFFFFFull));
    if (t == 0) idx_out[b * MS + m] = nx;
    float4 wp = s_pos4[nx];  // broadcast read
    lx = wp.x; ly = wp.y; lz = wp.z;
  }
}

// ---- radius(top-64) + MFMA-bf16 MLP + masked neighbor max (R3, proven) ----
__global__ __launch_bounds__(512, 4) void radconv_kernel(
    const float* __restrict__ x, const float* __restrict__ pos,
    const int* __restrict__ idx,
    const float* __restrict__ W1, const float* __restrict__ B1,
    const float* __restrict__ W2, const float* __restrict__ B2,
    const float* __restrict__ W3, const float* __restrict__ B3,
    float* __restrict__ out) {
  const int t = threadIdx.x;
  const int g = blockIdx.x >> 9;          // graph
  const int qpair = blockIdx.x & 511;     // 512 blocks/graph * 2 queries
  const float* pb = pos + (size_t)g * NPER * 3;
  const float* xb = x + (size_t)g * NPER * CIN;

  __shared__ int s_cnt[2];
  __shared__ float s_ctr[2][4];
  __shared__ __align__(16) unsigned long long s_list[2][LCAP];  // 6 KB
  __shared__ int s_nbr[2][64];
  __shared__ __align__(16) unsigned short sFeat[2][64 * 104];   // 26 KB (reused as red)
  __shared__ __align__(16) unsigned short sW1[64 * 104];        // 13 KB  [col][k<=96pad]
  __shared__ __align__(16) unsigned short sW2[64 * 72];         // 9 KB   [col][k=64+pad]
  __shared__ __align__(16) unsigned short sW3[128 * 72];        // 18 KB

  if (t < 2) s_cnt[t] = 0;
  const int q0 = g * MS + qpair * 2;
  const int qiA = idx[q0], qiB = idx[q0 + 1];
  const float cAx = pb[qiA * 3], cAy = pb[qiA * 3 + 1], cAz = pb[qiA * 3 + 2];
  const float cBx = pb[qiB * 3], cBy = pb[qiB * 3 + 1], cBz = pb[qiB * 3 + 2];
  if (t == 0) { s_ctr[0][0] = cAx; s_ctr[0][1] = cAy; s_ctr[0][2] = cAz; }
  if (t == 1) { s_ctr[1][0] = cBx; s_ctr[1][1] = cBy; s_ctr[1][2] = cBz; }
  __syncthreads();  // B1: s_cnt zeroed

  // ---- search: 8 pts/thread, both queries --------------------------------
  {
    float pp[24];
    const float4* pv = (const float4*)(pb + (size_t)t * 24);
#pragma unroll
    for (int r = 0; r < 6; ++r) {
      float4 v = pv[r];
      pp[r * 4 + 0] = v.x; pp[r * 4 + 1] = v.y;
      pp[r * 4 + 2] = v.z; pp[r * 4 + 3] = v.w;
    }
#pragma unroll
    for (int jj = 0; jj < 8; ++jj) {
      const int j = t * 8 + jj;
      const float X = pp[jj * 3], Y = pp[jj * 3 + 1], Z = pp[jj * 3 + 2];
      float dA = d2_exact(X, Y, Z, cAx, cAy, cAz);
      if (dA <= 0.04f) {  // f32(0.04) == JAX's R*R
        int p = atomicAdd(&s_cnt[0], 1);
        if (p < LCAP)
          s_list[0][p] = ((unsigned long long)__float_as_uint(dA) << 32) | (unsigned)j;
      }
      float dB = d2_exact(X, Y, Z, cBx, cBy, cBz);
      if (dB <= 0.04f) {
        int p = atomicAdd(&s_cnt[1], 1);
        if (p < LCAP)
          s_list[1][p] = ((unsigned long long)__float_as_uint(dB) << 32) | (unsigned)j;
      }
    }
  }
  // ---- stage weights (bf16, transposed) — independent of search ----------
  for (int ee = t; ee < 64 * 64; ee += 512) {           // zero W1 k-pad 67..103
    int c = ee >> 6, kk = 67 + (ee & 63);
    if (kk < 104) sW1[c * 104 + kk] = 0;
  }
  for (int e = t; e < 67 * 64; e += 512) {              // W1t[c][k] = W1[k][c]
    int k = e >> 6, c = e & 63;
    sW1[c * 104 + k] = f2bf(W1[e]);
  }
  for (int e = t; e < 64 * 64; e += 512) {
    int k = e >> 6, c = e & 63;
    sW2[c * 72 + k] = f2bf(W2[e]);
  }
  for (int e = t; e < 64 * 128; e += 512) {
    int k = e >> 7, c = e & 127;
    sW3[c * 72 + k] = f2bf(W3[e]);
  }
  __syncthreads();  // B2: lists + weights ready

  const int w = t >> 6, lane = t & 63;
  const int c0 = min(min(s_cnt[0], LCAP), 64);
  const int c1 = min(min(s_cnt[1], LCAP), 64);

  // ---- exact top-64 by (d2, idx) via rank; 4 waves per query -------------
  {
    const int rq = w >> 2;
    const int nsurv = min(s_cnt[rq], LCAP);
    for (int e = (w & 3) * 64 + lane; e < nsurv; e += 256) {
      unsigned long long mykey = s_list[rq][e];
      int rank = 0;
      int o = 0;
      for (; o + 8 <= nsurv; o += 8) {
        unsigned long long k0 = s_list[rq][o + 0], k1 = s_list[rq][o + 1];
        unsigned long long k2 = s_list[rq][o + 2], k3 = s_list[rq][o + 3];
        unsigned long long k4 = s_list[rq][o + 4], k5 = s_list[rq][o + 5];
        unsigned long long k6 = s_list[rq][o + 6], k7 = s_list[rq][o + 7];
        rank += (k0 < mykey) + (k1 < mykey) + (k2 < mykey) + (k3 < mykey) +
                (k4 < mykey) + (k5 < mykey) + (k6 < mykey) + (k7 < mykey);
      }
      for (; o < nsurv; ++o) rank += (s_list[rq][o] < mykey) ? 1 : 0;
      if (rank < 64) s_nbr[rq][rank] = (int)(mykey & 0xFFFFFFFFull);
    }
  }
  __syncthreads();  // B3: nbr lists ready

  // ---- gather feat rows: [x_j bf16 (64) | rel (3) | 0 pad ... 96) --------
  {
    const int slot = t >> 2, part = t & 3;   // 128 slots x 4 parts
    const int gq = slot >> 6, s = slot & 63;
    const int cq = gq ? c1 : c0;
    unsigned short* frow = &sFeat[gq][s * 104];
    uint4 z; z.x = z.y = z.z = z.w = 0u;
    if (s < cq) {
      const int j = s_nbr[gq][s];
      const float4* xr = (const float4*)(xb + (size_t)j * CIN + part * 16);
      float4 v0 = xr[0], v1 = xr[1], v2 = xr[2], v3 = xr[3];
      uint4 w0, w1;
      w0.x = f2bf(v0.x) | ((unsigned)f2bf(v0.y) << 16);
      w0.y = f2bf(v0.z) | ((unsigned)f2bf(v0.w) << 16);
      w0.z = f2bf(v1.x) | ((unsigned)f2bf(v1.y) << 16);
      w0.w = f2bf(v1.z) | ((unsigned)f2bf(v1.w) << 16);
      w1.x = f2bf(v2.x) | ((unsigned)f2bf(v2.y) << 16);
      w1.y = f2bf(v2.z) | ((unsigned)f2bf(v2.w) << 16);
      w1.z = f2bf(v3.x) | ((unsigned)f2bf(v3.y) << 16);
      w1.w = f2bf(v3.z) | ((unsigned)f2bf(v3.w) << 16);
      *(uint4*)(frow + part * 16) = w0;
      *(uint4*)(frow + part * 16 + 8) = w1;
      uint4 rz = z;
      if (part == 0) {
        const float cx = gq ? cBx : cAx, cy = gq ? cBy : cAy, cz = gq ? cBz : cAz;
        rz.x = f2bf(pb[j * 3] - cx) | ((unsigned)f2bf(pb[j * 3 + 1] - cy) << 16);
        rz.y = (unsigned)f2bf(pb[j * 3 + 2] - cz);
      }
      *(uint4*)(frow + 64 + part * 8) = rz;
    } else {
      *(uint4*)(frow + part * 16) = z;
      *(uint4*)(frow + part * 16 + 8) = z;
      *(uint4*)(frow + 64 + part * 8) = z;
    }
  }
  __syncthreads();  // B4: feat ready

  // ---- MFMA MLP: wave -> (query qq2, row tile mt) ------------------------
  const int qq2 = w >> 2;
  const int mt = w & 3;
  const int lo = lane & 15, hi = lane >> 4;
  unsigned short* F = &sFeat[qq2][0];
  const int arow = (16 * mt + lo) * 104;
  const int hrow = (16 * mt + hi * 4) * 104;

  {  // layer 1: K=96 (3 steps), N=64
    f32x4 acc[4];
#pragma unroll
    for (int n = 0; n < 4; ++n) {
      float bb = B1[n * 16 + lo];
      acc[n] = (f32x4){bb, bb, bb, bb};
    }
    s16x8 a0 = *(const s16x8*)(F + arow + 0 + hi * 8);
    s16x8 a1 = *(const s16x8*)(F + arow + 32 + hi * 8);
    s16x8 a2 = *(const s16x8*)(F + arow + 64 + hi * 8);
#pragma unroll
    for (int n = 0; n < 4; ++n) {
      const unsigned short* Bp = &sW1[(n * 16 + lo) * 104 + hi * 8];
      s16x8 b0 = *(const s16x8*)(Bp);
      s16x8 b1 = *(const s16x8*)(Bp + 32);
      s16x8 b2 = *(const s16x8*)(Bp + 64);
      acc[n] = __builtin_amdgcn_mfma_f32_16x16x32_bf16(a0, b0, acc[n], 0, 0, 0);
      acc[n] = __builtin_amdgcn_mfma_f32_16x16x32_bf16(a1, b1, acc[n], 0, 0, 0);
      acc[n] = __builtin_amdgcn_mfma_f32_16x16x32_bf16(a2, b2, acc[n], 0, 0, 0);
    }
#pragma unroll
    for (int n = 0; n < 4; ++n)
#pragma unroll
      for (int r = 0; r < 4; ++r)
        F[hrow + r * 104 + n * 16 + lo] = f2bf(fmaxf(acc[n][r], 0.f));
  }
  {  // layer 2: K=64 (2 steps), N=64
    f32x4 acc[4];
#pragma unroll
    for (int n = 0; n < 4; ++n) {
      float bb = B2[n * 16 + lo];
      acc[n] = (f32x4){bb, bb, bb, bb};
    }
    s16x8 a0 = *(const s16x8*)(F + arow + 0 + hi * 8);
    s16x8 a1 = *(const s16x8*)(F + arow + 32 + hi * 8);
#pragma unroll
    for (int n = 0; n < 4; ++n) {
      const unsigned short* Bp = &sW2[(n * 16 + lo) * 72 + hi * 8];
      s16x8 b0 = *(const s16x8*)(Bp);
      s16x8 b1 = *(const s16x8*)(Bp + 32);
      acc[n] = __builtin_amdgcn_mfma_f32_16x16x32_bf16(a0, b0, acc[n], 0, 0, 0);
      acc[n] = __builtin_amdgcn_mfma_f32_16x16x32_bf16(a1, b1, acc[n], 0, 0, 0);
    }
#pragma unroll
    for (int n = 0; n < 4; ++n)
#pragma unroll
      for (int r = 0; r < 4; ++r)
        F[hrow + r * 104 + n * 16 + lo] = f2bf(fmaxf(acc[n][r], 0.f));
  }
  float pm[8];
  {  // layer 3: K=64 (2 steps), N=128, fused masked row-max
    const int cq = qq2 ? c1 : c0;
    f32x4 acc[8];
#pragma unroll
    for (int n = 0; n < 8; ++n) {
      float bb = B3[n * 16 + lo];
      acc[n] = (f32x4){bb, bb, bb, bb};
    }
    s16x8 a0 = *(const s16x8*)(F + arow + 0 + hi * 8);
    s16x8 a1 = *(const s16x8*)(F + arow + 32 + hi * 8);
#pragma unroll
    for (int n = 0; n < 8; ++n) {
      const unsigned short* Bp = &sW3[(n * 16 + lo) * 72 + hi * 8];
      s16x8 b0 = *(const s16x8*)(Bp);
      s16x8 b1 = *(const s16x8*)(Bp + 32);
      acc[n] = __builtin_amdgcn_mfma_f32_16x16x32_bf16(a0, b0, acc[n], 0, 0, 0);
      acc[n] = __builtin_amdgcn_mfma_f32_16x16x32_bf16(a1, b1, acc[n], 0, 0, 0);
    }
#pragma unroll
    for (int n = 0; n < 8; ++n) {
      float v = -1e30f;
#pragma unroll
      for (int r = 0; r < 4; ++r) {
        int row = 16 * mt + hi * 4 + r;
        if (row < cq) v = fmaxf(v, fmaxf(acc[n][r], 0.f));
      }
      pm[n] = v;
    }
  }
  __syncthreads();  // B5: all sFeat reads done -> reuse as reduction buffer

  float* red = (float*)&sFeat[0][0];  // [2][128][17] floats
#pragma unroll
  for (int n = 0; n < 8; ++n)
    red[((qq2 * 128) + n * 16 + lo) * 17 + mt * 4 + hi] = pm[n];
  __syncthreads();  // B6

  if (t < 256) {
    const int gq = t >> 7, cc = t & 127;
    const float* rp = red + (gq * 128 + cc) * 17;
    float v = rp[0];
#pragma unroll
    for (int p = 1; p < 16; ++p) v = fmaxf(v, rp[p]);
    out[(size_t)(q0 + gq) * 128 + cc] = v;
  }
  if (t == 256 || t == 257) {
    const int gq = t - 256;
    const int qrow = q0 + gq;
    out[524288 + qrow * 3 + 0] = s_ctr[gq][0];
    out[524288 + qrow * 3 + 1] = s_ctr[gq][1];
    out[524288 + qrow * 3 + 2] = s_ctr[gq][2];
    out[536576 + qrow] = (float)g;
  }
}

extern "C" void kernel_launch(void* const* d_in, const int* in_sizes, int n_in,
                              void* d_out, int out_size, void* d_ws, size_t ws_size,
                              hipStream_t stream) {
  const float* x   = (const float*)d_in[0];
  const float* pos = (const float*)d_in[1];
  const float* W1  = (const float*)d_in[3];
  const float* B1  = (const float*)d_in[4];
  const float* W2  = (const float*)d_in[5];
  const float* B2  = (const float*)d_in[6];
  const float* W3  = (const float*)d_in[7];
  const float* B3  = (const float*)d_in[8];
  float* out = (float*)d_out;
  int* idx = (int*)d_ws;  // 4096 ints

  fps_kernel<<<4, 256, 0, stream>>>(pos, idx);
  radconv_kernel<<<2048, 512, 0, stream>>>(x, pos, idx, W1, B1, W2, B2, W3, B3, out);
}